// Round 6
// baseline (12363.489 us; speedup 1.0000x reference)
//
#include <hip/hip_runtime.h>
#include <hip/hip_bf16.h>

namespace {

constexpr int B = 1024, T = 512, H = 60, G = 180;
constexpr int NTHR = 192;    // scalar kernel
constexpr int NTHRV = 384;   // vec kernel: 2 threads per gate-row (half-row split)
constexpr int TT = 8;        // time-tile depth for the fused input gemm
constexpr int NT = T / TT;

__device__ __forceinline__ float sigm(float x) { return 1.f / (1.f + __expf(-x)); }
__device__ __forceinline__ float tanh_fast(float x) {
  x = fminf(fmaxf(x, -15.f), 15.f);
  const float e = __expf(-2.f * x);
  return (1.f - e) / (1.f + e);
}

__device__ __forceinline__ float ldcvt(const float* p) { return *p; }
__device__ __forceinline__ float ldcvt(const __hip_bfloat16* p) { return __bfloat162float(*p); }
__device__ __forceinline__ void stcvt(float* p, float v) { *p = v; }
__device__ __forceinline__ void stcvt(__hip_bfloat16* p, float v) { *p = __float2bfloat16(v); }

// ---------------------------------------------------------------------------
// Scalar-input GRU layer (F=1). Unchanged from round 5: ~62 us, proven shape.
// ---------------------------------------------------------------------------
#define ACCH(i, dst)                                                  \
  {                                                                   \
    const float4 hv = *(const float4*)&h_sh[(i) * 4];                 \
    dst = fmaf(Wh##i.x, hv.x, dst);                                   \
    dst = fmaf(Wh##i.y, hv.y, dst);                                   \
    dst = fmaf(Wh##i.z, hv.z, dst);                                   \
    dst = fmaf(Wh##i.w, hv.w, dst);                                   \
  }

template <typename TS, bool WRITE_YS, bool WRITE_ENC>
__global__ __launch_bounds__(NTHR, 1) void gru_scalar_kernel(
    const float* __restrict__ xscalar,  // [B][T]
    const float* __restrict__ Wih,      // [180][1]
    const float* __restrict__ Whh,      // [180][60]
    const float* __restrict__ bih, const float* __restrict__ bhh,
    const float* __restrict__ h_init,   // nullptr => zeros; [b*180 + j]
    TS* __restrict__ ys_out,            // [T][B][H]
    float* __restrict__ enc_out)        // pre-offset by slot; [b*180 + j]
{
  const int tid = threadIdx.x;
  const int b = blockIdx.x;

  __shared__ __align__(16) float h_sh[64];
  __shared__ float Ar[60], Az[60], Nn[60], Hn[60];
  __shared__ float xs_seq[T];

  const int rr = (tid < G) ? tid : 0;

  float4 Wh0, Wh1, Wh2, Wh3, Wh4, Wh5, Wh6, Wh7, Wh8, Wh9, Wh10, Wh11, Wh12, Wh13, Wh14;
#define LWH(i) Wh##i = *(const float4*)&Whh[(size_t)rr * H + (i) * 4];
  LWH(0) LWH(1) LWH(2) LWH(3) LWH(4) LWH(5) LWH(6) LWH(7)
  LWH(8) LWH(9) LWH(10) LWH(11) LWH(12) LWH(13) LWH(14)
#undef LWH
  const float wih0 = Wih[rr];
  const float bi = bih[rr];
  const float bh = bhh[rr];

  if (tid < H) h_sh[tid] = h_init ? h_init[(size_t)b * G + tid] : 0.f;
  if (tid >= H && tid < 64) h_sh[tid] = 0.f;
  for (int i = tid; i < T; i += NTHR) xs_seq[i] = xscalar[(size_t)b * T + i];
  __syncthreads();

  const int g = tid / H;
  const int j = tid - g * H;

  for (int t = 0; t < T; ++t) {
    if (tid < G) {
      float c0 = bh, c1 = 0.f, c2 = 0.f, c3 = 0.f;
      ACCH(0, c0) ACCH(1, c1) ACCH(2, c2) ACCH(3, c3)
      ACCH(4, c0) ACCH(5, c1) ACCH(6, c2) ACCH(7, c3)
      ACCH(8, c0) ACCH(9, c1) ACCH(10, c2) ACCH(11, c3)
      ACCH(12, c0) ACCH(13, c1) ACCH(14, c2)
      const float c = (c0 + c1) + (c2 + c3);
      const float a = fmaf(wih0, xs_seq[t], bi);
      if (g == 0)       Ar[j] = a + c;
      else if (g == 1)  Az[j] = a + c;
      else            { Nn[j] = a; Hn[j] = c; }
    }
    __syncthreads();

    if (tid < H) {
      const float rg = sigm(Ar[tid]);
      const float zg = sigm(Az[tid]);
      const float nv = tanh_fast(fmaf(rg, Hn[tid], Nn[tid]));
      const float hnew = fmaf(zg, h_sh[tid] - nv, nv);
      h_sh[tid] = hnew;
      if constexpr (WRITE_YS)
        stcvt(&ys_out[(size_t)t * B * H + (size_t)b * H + tid], hnew);
    }
    __syncthreads();
  }

  if constexpr (WRITE_ENC) {
    if (tid < H) enc_out[(size_t)b * G + tid] = h_sh[tid];
  }
}

// ---------------------------------------------------------------------------
// Vector-input GRU layer, half-row split:
//   384 threads; thread (hf, r) = (tid/180, tid%180) owns HALF of gate-row r
//   (30 floats, cols hf*32..): peak live weight state ~32 floats/thread --
//   inside the backend's demonstrated ~68-88 VGPR comfort zone (rounds 1-5:
//   it refuses to hold 60+, spilling with ~200-cyc reload latency per step).
//   Partial dot-products meet in LDS; the 60-thread activation phase sums
//   2 gi-halves + 2 c-halves per gate.
//   Per 8-step tile: prefetch next x-tile -> fused ih-gemm (Wih half-row
//   reloaded per tile from L1/L2, 8 static accumulators) -> 8 rec steps.
// ---------------------------------------------------------------------------
template <typename TS, bool WRITE_YS, bool WRITE_ENC, bool WRITE_PRED>
__global__ __launch_bounds__(NTHRV, 1) void gru_vec_kernel(
    const TS* __restrict__ xseq,        // [T][B][H]
    const float* __restrict__ Wih,      // [180][60]
    const float* __restrict__ Whh,      // [180][60]
    const float* __restrict__ bih, const float* __restrict__ bhh,
    const float* __restrict__ h_init,   // nullptr => zeros; [b*180 + j]
    TS* __restrict__ ys_out,            // [T][B][H]
    float* __restrict__ enc_out,        // pre-offset by slot; [b*180 + j]
    float* __restrict__ pred_out,       // [B][T]
    const float* __restrict__ lin_W,    // [60]
    const float* __restrict__ lin_b)    // [1]
{
  const int tid = threadIdx.x;
  const int b = blockIdx.x;

  __shared__ __align__(16) float h_sh[64];            // h[60] + zero pad
  __shared__ __align__(16) float x_sh[2][TT][64];     // x tiles, cols 60..63 = 0
  __shared__ float gip[2][TT][184];                   // ih-gemm partials per half
  __shared__ float cpart[2][3 * 64];                  // hh partials per half
  __shared__ float pv[64];

  const bool act = tid < 2 * G;          // 360 matmul threads
  const int hf = (tid >= G) ? 1 : 0;     // which half of the dot
  const int r = act ? (tid - hf * G) : 0;
  const int off = hf * 32;               // column offset of this half

  // ---- persistent: HALF a Whh row (8 float4; hf1's 8th is zero-padded) ----
  float4 Wh0, Wh1, Wh2, Wh3, Wh4, Wh5, Wh6, Wh7;
#define LWHH(i) Wh##i = *(const float4*)&Whh[(size_t)r * H + off + (i) * 4];
  LWHH(0) LWHH(1) LWHH(2) LWHH(3) LWHH(4) LWHH(5) LWHH(6)
#undef LWHH
  Wh7 = (hf == 0) ? *(const float4*)&Whh[(size_t)r * H + 28] : make_float4(0, 0, 0, 0);
  const float bi = (hf == 0) ? bih[r] : 0.f;
  const float bh = (hf == 0) ? bhh[r] : 0.f;

  float linw = 0.f, linb = 0.f;
  if constexpr (WRITE_PRED) {
    linw = lin_W[tid < H ? tid : 0];
    linb = lin_b[0];
  }

  // ---- init h, zero pads, stage tile 0 ----
  if (tid < 64) h_sh[tid] = (tid < H && h_init) ? h_init[(size_t)b * G + tid] : 0.f;
  if (tid < 2 * TT) {  // zero x_sh col pads once
    float4* p = (float4*)&x_sh[tid / TT][tid % TT][60];
    *p = make_float4(0, 0, 0, 0);
  }
  {
    const int e0 = tid, e1 = tid + NTHRV;
    {
      const int s = e0 / H, hh = e0 - s * H;
      if (e0 < TT * H) x_sh[0][s][hh] = ldcvt(&xseq[((size_t)s * B + b) * H + hh]);
    }
    if (e1 < TT * H) {
      const int s = e1 / H, hh = e1 - s * H;
      x_sh[0][s][hh] = ldcvt(&xseq[((size_t)s * B + b) * H + hh]);
    }
  }
  __syncthreads();

  const int g = r / H;                   // gate 0:r 1:z 2:n
  const int j = r - g * H;
  const int cidx = hf * 192 + g * 64 + j;  // cpart flat index
  float* cp = &((float*)cpart)[cidx];

  for (int tile = 0; tile < NT; ++tile) {
    const int cur = tile & 1, nxt = cur ^ 1;

    // --- prefetch next x tile into registers (hidden under gemm+rec) ---
    float xr0 = 0.f, xr1 = 0.f;
    const int e0 = tid, e1 = tid + NTHRV;
    if (tile + 1 < NT) {
      const size_t tb = (size_t)(tile + 1) * TT;
      if (e0 < TT * H) {
        const int s = e0 / H, hh = e0 - s * H;
        xr0 = ldcvt(&xseq[((tb + s) * B + b) * H + hh]);
      }
      if (e1 < TT * H) {
        const int s = e1 / H, hh = e1 - s * H;
        xr1 = ldcvt(&xseq[((tb + s) * B + b) * H + hh]);
      }
    }

    // --- fused ih-gemm: gip[hf][s][r] = (hf? 0:bi) + Wih[r][off:off+32].x ---
    if (act) {
      float a0 = bi, a1 = bi, a2 = bi, a3 = bi, a4 = bi, a5 = bi, a6 = bi, a7 = bi;
#pragma unroll
      for (int k = 0; k < 8; ++k) {
        float4 w = make_float4(0, 0, 0, 0);
        if (hf == 0 || k < 7) w = *(const float4*)&Wih[(size_t)r * H + off + k * 4];
#define GX(s, a)                                                      \
        {                                                             \
          const float4 xv = *(const float4*)&x_sh[cur][s][off + k * 4];\
          a = fmaf(w.x, xv.x, a); a = fmaf(w.y, xv.y, a);             \
          a = fmaf(w.z, xv.z, a); a = fmaf(w.w, xv.w, a);             \
        }
        GX(0, a0) GX(1, a1) GX(2, a2) GX(3, a3)
        GX(4, a4) GX(5, a5) GX(6, a6) GX(7, a7)
#undef GX
      }
      gip[hf][0][r] = a0; gip[hf][1][r] = a1; gip[hf][2][r] = a2; gip[hf][3][r] = a3;
      gip[hf][4][r] = a4; gip[hf][5][r] = a5; gip[hf][6][r] = a6; gip[hf][7][r] = a7;
    }

    // --- write prefetched x into the other buffer ---
    if (tile + 1 < NT) {
      if (e0 < TT * H) { const int s = e0 / H, hh = e0 - s * H; x_sh[nxt][s][hh] = xr0; }
      if (e1 < TT * H) { const int s = e1 / H, hh = e1 - s * H; x_sh[nxt][s][hh] = xr1; }
    }
    // no extra barrier: gip/x_sh[nxt] become visible at the step-0 barrier

    // --- 8 recurrent steps ---
#pragma unroll 1
    for (int s = 0; s < TT; ++s) {
      const int t = tile * TT + s;
      if (act) {
        float c0 = bh, c1 = 0.f;
#define HC(i, dst)                                                    \
        {                                                             \
          const float4 hv = *(const float4*)&h_sh[off + (i) * 4];     \
          dst = fmaf(Wh##i.x, hv.x, dst); dst = fmaf(Wh##i.y, hv.y, dst); \
          dst = fmaf(Wh##i.z, hv.z, dst); dst = fmaf(Wh##i.w, hv.w, dst); \
        }
        HC(0, c0) HC(1, c1) HC(2, c0) HC(3, c1)
        HC(4, c0) HC(5, c1) HC(6, c0) HC(7, c1)
#undef HC
        *cp = c0 + c1;
      }
      __syncthreads();

      if (tid < H) {
        const float pr = gip[0][s][tid]       + gip[1][s][tid]
                       + cpart[0][tid]        + cpart[1][tid];
        const float pz = gip[0][s][H + tid]   + gip[1][s][H + tid]
                       + cpart[0][64 + tid]   + cpart[1][64 + tid];
        const float pa = gip[0][s][2 * H + tid] + gip[1][s][2 * H + tid];
        const float pc = cpart[0][128 + tid]  + cpart[1][128 + tid];
        const float rg = sigm(pr);
        const float zg = sigm(pz);
        const float nv = tanh_fast(fmaf(rg, pc, pa));
        const float hnew = fmaf(zg, h_sh[tid] - nv, nv);
        h_sh[tid] = hnew;
        if constexpr (WRITE_YS)
          stcvt(&ys_out[(size_t)t * B * H + (size_t)b * H + tid], hnew);
        if constexpr (WRITE_PRED) pv[tid] = hnew * linw;
      }
      __syncthreads();

      if constexpr (WRITE_PRED) {
        if (tid < 64) {
          float v = (tid < H) ? pv[tid] : 0.f;
#pragma unroll
          for (int o = 32; o; o >>= 1) v += __shfl_xor(v, o);
          if (tid == 0) pred_out[(size_t)b * T + t] = v + linb;
        }
      }
    }
  }

  if constexpr (WRITE_ENC) {
    if (tid < H) enc_out[(size_t)b * G + tid] = h_sh[tid];
  }
}

template <typename TS>
void launch_all(const float* inputs, const float* outputs,
                const float* eW_ih0, const float* eW_hh0, const float* eb_ih0, const float* eb_hh0,
                const float* eW_ih1, const float* eW_hh1, const float* eb_ih1, const float* eb_hh1,
                const float* eW_ih2, const float* eW_hh2, const float* eb_ih2, const float* eb_hh2,
                const float* c1_Wih, const float* c1_Whh, const float* c1_bih, const float* c1_bhh,
                const float* c2_Wih, const float* c2_Whh, const float* c2_bih, const float* c2_bhh,
                const float* c3_Wih, const float* c3_Whh, const float* c3_bih, const float* c3_bhh,
                const float* lin_W, const float* lin_b,
                float* pred, float* enc, void* d_ws, hipStream_t stream) {
  const size_t seq = (size_t)T * B * H;
  TS* ws0 = (TS*)d_ws;
  TS* ws1 = ws0 + seq;
  const dim3 grid(B), blk(NTHR), blkv(NTHRV);

  // encoder
  gru_scalar_kernel<TS, true, true><<<grid, blk, 0, stream>>>(
      inputs, eW_ih0, eW_hh0, eb_ih0, eb_hh0, nullptr, ws0, enc + 0);
  gru_vec_kernel<TS, true, true, false><<<grid, blkv, 0, stream>>>(
      ws0, eW_ih1, eW_hh1, eb_ih1, eb_hh1, nullptr,
      ws1, enc + 60, nullptr, nullptr, nullptr);
  gru_vec_kernel<TS, false, true, false><<<grid, blkv, 0, stream>>>(
      ws1, eW_ih2, eW_hh2, eb_ih2, eb_hh2, nullptr,
      nullptr, enc + 120, nullptr, nullptr, nullptr);
  // decoder: h1<-enc[2], h2<-enc[1], h3<-enc[0]
  gru_scalar_kernel<TS, true, false><<<grid, blk, 0, stream>>>(
      outputs, c1_Wih, c1_Whh, c1_bih, c1_bhh, enc + 120, ws0, nullptr);
  gru_vec_kernel<TS, true, false, false><<<grid, blkv, 0, stream>>>(
      ws0, c2_Wih, c2_Whh, c2_bih, c2_bhh, enc + 60,
      ws1, nullptr, nullptr, nullptr, nullptr);
  gru_vec_kernel<TS, false, false, true><<<grid, blkv, 0, stream>>>(
      ws1, c3_Wih, c3_Whh, c3_bih, c3_bhh, enc + 0,
      nullptr, nullptr, pred, lin_W, lin_b);
}

}  // namespace

extern "C" void kernel_launch(void* const* d_in, const int* in_sizes, int n_in,
                              void* d_out, int out_size, void* d_ws, size_t ws_size,
                              hipStream_t stream) {
  const float* inputs  = (const float*)d_in[0];
  const float* outputs = (const float*)d_in[1];
  const float* eW_ih0 = (const float*)d_in[2];  const float* eW_hh0 = (const float*)d_in[3];
  const float* eb_ih0 = (const float*)d_in[4];  const float* eb_hh0 = (const float*)d_in[5];
  const float* eW_ih1 = (const float*)d_in[6];  const float* eW_hh1 = (const float*)d_in[7];
  const float* eb_ih1 = (const float*)d_in[8];  const float* eb_hh1 = (const float*)d_in[9];
  const float* eW_ih2 = (const float*)d_in[10]; const float* eW_hh2 = (const float*)d_in[11];
  const float* eb_ih2 = (const float*)d_in[12]; const float* eb_hh2 = (const float*)d_in[13];
  const float* c1_Wih = (const float*)d_in[14]; const float* c1_Whh = (const float*)d_in[15];
  const float* c1_bih = (const float*)d_in[16]; const float* c1_bhh = (const float*)d_in[17];
  const float* c2_Wih = (const float*)d_in[18]; const float* c2_Whh = (const float*)d_in[19];
  const float* c2_bih = (const float*)d_in[20]; const float* c2_bhh = (const float*)d_in[21];
  const float* c3_Wih = (const float*)d_in[22]; const float* c3_Whh = (const float*)d_in[23];
  const float* c3_bih = (const float*)d_in[24]; const float* c3_bhh = (const float*)d_in[25];
  const float* lin_W  = (const float*)d_in[26]; const float* lin_b  = (const float*)d_in[27];

  float* pred = (float*)d_out;                 // [B][T]
  float* enc  = pred + (size_t)B * T;          // [B][3][H]

  const size_t seq = (size_t)T * B * H;

#define ARGS inputs, outputs, \
    eW_ih0, eW_hh0, eb_ih0, eb_hh0, eW_ih1, eW_hh1, eb_ih1, eb_hh1, \
    eW_ih2, eW_hh2, eb_ih2, eb_hh2, \
    c1_Wih, c1_Whh, c1_bih, c1_bhh, c2_Wih, c2_Whh, c2_bih, c2_bhh, \
    c3_Wih, c3_Whh, c3_bih, c3_bhh, lin_W, lin_b, pred, enc, d_ws, stream

  if (ws_size >= 2 * seq * sizeof(float)) {
    launch_all<float>(ARGS);            // 252 MB (known to fit)
  } else {
    launch_all<__hip_bfloat16>(ARGS);   // 126 MB fallback
  }
#undef ARGS
}

// Round 7
// 3809.534 us; speedup vs baseline: 3.2454x; 3.2454x over previous
//
#include <hip/hip_runtime.h>
#include <hip/hip_bf16.h>

namespace {

constexpr int B = 1024, T = 512, H = 60, G = 180;
constexpr int NTHR = 960;  // 5 groups x 192 threads (3 waves each)

__device__ __forceinline__ float sigm(float x) { return 1.f / (1.f + __expf(-x)); }
__device__ __forceinline__ float tanh_fast(float x) {
  x = fminf(fmaxf(x, -15.f), 15.f);
  const float e = __expf(-2.f * x);
  return (1.f - e) / (1.f + e);
}

// ---------------------------------------------------------------------------
// 3-layer GRU stack, software-pipelined inside one block (one batch element).
// Groups (192 thr = 3 waves each; thread owns ONE 60-float weight row):
//   gid0: L0 recurrence (Whh0 row) + scalar-input term  -> target step k
//   gid1: feed1 = Wih1 . h0 + bih1 -> LDS ring          -> target k-1
//   gid2: L1 recurrence (Whh1 row)                      -> target k-2
//   gid3: feed2 = Wih2 . h1 + bih2 -> LDS ring          -> target k-3
//   gid4: L2 recurrence (Whh2 row)                      -> target k-4
// All groups execute the IDENTICAL 60-FMA broadcast-LDS dot per step (the
// proven no-spill scalar-kernel shape). 2 barriers/step. No intermediate
// global traffic at all. Decoder variant fuses the linear head (pv parity
// double-buffer; reduce done by the otherwise-idle wave 3 one step later).
// ---------------------------------------------------------------------------
template <bool IS_DEC>
__global__ __launch_bounds__(NTHR, 1) void gru3_pipe_kernel(
    const float* __restrict__ xsc,    // [B][T] scalar input stream
    const float* __restrict__ W0ih, const float* __restrict__ b0ih,  // [180][1],[180]
    const float* __restrict__ W0hh, const float* __restrict__ b0hh,  // [180][60]
    const float* __restrict__ W1ih, const float* __restrict__ b1ih,
    const float* __restrict__ W1hh, const float* __restrict__ b1hh,
    const float* __restrict__ W2ih, const float* __restrict__ b2ih,
    const float* __restrict__ W2hh, const float* __restrict__ b2hh,
    float* __restrict__ encbuf,       // [B][3][60]: enc writes; dec reads init
    float* __restrict__ pred,         // [B][T] (dec only)
    const float* __restrict__ linW,   // [60]
    const float* __restrict__ linb)   // [1]
{
  const int tid = threadIdx.x;
  const int b = blockIdx.x;

  __shared__ __align__(16) float hfl[3 * 64];   // h0,h1,h2 (60 + pad)
  __shared__ float gates[3][4][64];             // per layer: r,z,n(gi),n(hh)
  __shared__ float ring[2][2][192];             // gi1, gi2: 2-slot parity rings
  __shared__ float xs[T];                       // scalar input sequence
  __shared__ float pv[2][64];                   // linear-head partials (parity)

  const int gid = tid / 192;            // wave-uniform (192 = 3 full waves)
  const int rr0 = tid - gid * 192;
  const bool rowact = rr0 < G;
  const int rr = rowact ? rr0 : 0;
  const int gg = rr / H;                // gate 0:r 1:z 2:n
  const int jj = rr - gg * H;

  // ---- per-group weight row (exactly 60 floats/thread, named float4s) ----
  const float* wsrc; const float* bsrc;
  switch (gid) {
    case 0:  wsrc = W0hh; bsrc = b0hh; break;
    case 1:  wsrc = W1ih; bsrc = b1ih; break;
    case 2:  wsrc = W1hh; bsrc = b1hh; break;
    case 3:  wsrc = W2ih; bsrc = b2ih; break;
    default: wsrc = W2hh; bsrc = b2hh; break;
  }
  wsrc += (size_t)rr * H;

  float4 Wv0, Wv1, Wv2, Wv3, Wv4, Wv5, Wv6, Wv7, Wv8, Wv9, Wv10, Wv11, Wv12, Wv13, Wv14;
#define LW(i) Wv##i = *(const float4*)(wsrc + (i) * 4);
  LW(0) LW(1) LW(2) LW(3) LW(4) LW(5) LW(6) LW(7)
  LW(8) LW(9) LW(10) LW(11) LW(12) LW(13) LW(14)
#undef LW
  const float bias = bsrc[rr];          // bhh for rec rows, bih_next for feeds

  float wih0 = 0.f, bi0 = 0.f;
  if (gid == 0) { wih0 = W0ih[rr]; bi0 = b0ih[rr]; }

  float linw = 0.f, lb = 0.f;
  if constexpr (IS_DEC) {
    if (tid >= 120 && tid < 180) linw = linW[tid - 120];
    lb = linb[0];
  }

  // ---- init h (enc: zeros; dec: enc slots, layer l <- slot 2-l) ----
  if (tid < 192) {
    const int l = tid >> 6, j = tid & 63;
    float hv = 0.f;
    if (j < H) {
      if constexpr (IS_DEC) hv = encbuf[(size_t)b * G + (2 - l) * H + j];
    }
    hfl[tid] = hv;
  }
  for (int i = tid; i < T; i += NTHR) xs[i] = xsc[(size_t)b * T + i];
  __syncthreads();

  const float* hsrc = &hfl[(gid >> 1) * 64];  // gid0,1->h0  gid2,3->h1  gid4->h2
  const int l_act = (tid < G) ? tid / H : 0;
  const int j_act = (tid < G) ? tid - l_act * H : 0;

  const int K = IS_DEC ? (T + 5) : (T + 4);

  for (int k = 0; k < K; ++k) {
    // ================= phase 1: all dot groups in parallel =================
    const unsigned tgt = (unsigned)(k - gid);   // this group's target step
    if (rowact && tgt < (unsigned)T) {
      const float4* hv4 = (const float4*)hsrc;
      float c0 = bias, c1 = 0.f, c2 = 0.f, c3 = 0.f;
#define AC(i, d)                                                        \
      { const float4 hv = hv4[i];                                       \
        d = fmaf(Wv##i.x, hv.x, d); d = fmaf(Wv##i.y, hv.y, d);         \
        d = fmaf(Wv##i.z, hv.z, d); d = fmaf(Wv##i.w, hv.w, d); }
      AC(0, c0) AC(1, c1) AC(2, c2) AC(3, c3)
      AC(4, c0) AC(5, c1) AC(6, c2) AC(7, c3)
      AC(8, c0) AC(9, c1) AC(10, c2) AC(11, c3)
      AC(12, c0) AC(13, c1) AC(14, c2)
#undef AC
      const float c = (c0 + c1) + (c2 + c3);
      if ((gid & 1) == 0) {
        // recurrence group for layer lrec: route gate pre-activations
        const int lrec = gid >> 1;
        float a;
        if (gid == 0) a = fmaf(wih0, xs[k], bi0);                 // L0 gi
        else          a = ring[lrec - 1][(k & 1) ^ 1][rr];        // from feed
        if (gg == 2) { gates[lrec][2][jj] = a; gates[lrec][3][jj] = c; }
        else           gates[lrec][gg][jj] = a + c;
      } else {
        // feed group: gi_{next}[target] into its parity ring slot
        ring[gid >> 1][k & 1][rr] = c;
      }
    }
    __syncthreads();

    // ================= phase 2: activations (+ fused linear head) =========
    if (tid < G) {
      const unsigned tl = (unsigned)(k - 2 * l_act);
      if (tl < (unsigned)T) {
        const float pr = gates[l_act][0][j_act];
        const float pz = gates[l_act][1][j_act];
        const float pa = gates[l_act][2][j_act];
        const float pc = gates[l_act][3][j_act];
        const float rg = sigm(pr), zg = sigm(pz);
        const float nv = tanh_fast(fmaf(rg, pc, pa));
        const float hold = hfl[l_act * 64 + j_act];
        const float hnew = fmaf(zg, hold - nv, nv);   // (1-z)n + z h
        hfl[l_act * 64 + j_act] = hnew;
        if constexpr (IS_DEC) {
          if (l_act == 2) pv[k & 1][j_act] = hnew * linw;
        }
      }
    }
    if constexpr (IS_DEC) {
      // wave 3 (feed1 rows, idle in phase 2) reduces last step's pv
      if (tid >= 192 && tid < 256) {
        const unsigned tp = (unsigned)(k - 5);
        if (tp < (unsigned)T) {
          const int lane = tid - 192;
          float v = (lane < H) ? pv[(k - 1) & 1][lane] : 0.f;
#pragma unroll
          for (int o = 32; o; o >>= 1) v += __shfl_xor(v, o);
          if (lane == 0) pred[(size_t)b * T + tp] = v + lb;
        }
      }
    }
    __syncthreads();
  }

  if constexpr (!IS_DEC) {
    // final hidden states -> encoded_vec, layout [B][3][60], slot l = layer l
    if (tid < G) encbuf[(size_t)b * G + tid] = hfl[l_act * 64 + j_act];
  }
}

}  // namespace

extern "C" void kernel_launch(void* const* d_in, const int* in_sizes, int n_in,
                              void* d_out, int out_size, void* d_ws, size_t ws_size,
                              hipStream_t stream) {
  const float* inputs  = (const float*)d_in[0];
  const float* outputs = (const float*)d_in[1];
  const float* eW_ih0 = (const float*)d_in[2];  const float* eW_hh0 = (const float*)d_in[3];
  const float* eb_ih0 = (const float*)d_in[4];  const float* eb_hh0 = (const float*)d_in[5];
  const float* eW_ih1 = (const float*)d_in[6];  const float* eW_hh1 = (const float*)d_in[7];
  const float* eb_ih1 = (const float*)d_in[8];  const float* eb_hh1 = (const float*)d_in[9];
  const float* eW_ih2 = (const float*)d_in[10]; const float* eW_hh2 = (const float*)d_in[11];
  const float* eb_ih2 = (const float*)d_in[12]; const float* eb_hh2 = (const float*)d_in[13];
  const float* c1_Wih = (const float*)d_in[14]; const float* c1_Whh = (const float*)d_in[15];
  const float* c1_bih = (const float*)d_in[16]; const float* c1_bhh = (const float*)d_in[17];
  const float* c2_Wih = (const float*)d_in[18]; const float* c2_Whh = (const float*)d_in[19];
  const float* c2_bih = (const float*)d_in[20]; const float* c2_bhh = (const float*)d_in[21];
  const float* c3_Wih = (const float*)d_in[22]; const float* c3_Whh = (const float*)d_in[23];
  const float* c3_bih = (const float*)d_in[24]; const float* c3_bhh = (const float*)d_in[25];
  const float* lin_W  = (const float*)d_in[26]; const float* lin_b  = (const float*)d_in[27];

  float* pred = (float*)d_out;                 // [B][T]
  float* enc  = pred + (size_t)B * T;          // [B][3][60]

  (void)d_ws; (void)ws_size;  // unused: no intermediate global streams

  // encoder: 3-layer stack pipelined in one kernel
  gru3_pipe_kernel<false><<<dim3(B), dim3(NTHR), 0, stream>>>(
      inputs,
      eW_ih0, eb_ih0, eW_hh0, eb_hh0,
      eW_ih1, eb_ih1, eW_hh1, eb_hh1,
      eW_ih2, eb_ih2, eW_hh2, eb_hh2,
      enc, pred, lin_W, lin_b);

  // decoder: 3 stacked GRU cells + linear head, same pipeline
  gru3_pipe_kernel<true><<<dim3(B), dim3(NTHR), 0, stream>>>(
      outputs,
      c1_Wih, c1_bih, c1_Whh, c1_bhh,
      c2_Wih, c2_bih, c2_Whh, c2_bhh,
      c3_Wih, c3_bih, c3_Whh, c3_bhh,
      enc, pred, lin_W, lin_b);
}